// Round 2
// baseline (7396.238 us; speedup 1.0000x reference)
//
#include <hip/hip_runtime.h>

// Problem constants (match reference)
#define BATCH 4
#define CH    96      // in channels == hid
#define HH    160
#define WW    320
#define MAXD  49
#define BN_EPS 1e-5f
#define SLOPE  0.01f

// ---------------------------------------------------------------------------
// Fused feature kernel: 3x3 conv (SAME) + BN(inference) + LeakyReLU + 1x1 desc
// + L2-normalize over channels. One pixel per thread, 8x32 pixel tile/block.
// Conv/desc weights are read at wave-uniform addresses -> compiler emits
// scalar loads, leaving the VALU for the FMA stream. zacc[96] lives in VGPRs
// (every loop indexing it is fully unrolled -> static indices, no scratch).
// ---------------------------------------------------------------------------
__launch_bounds__(256, 1)
__global__ void feat_kernel(const float* __restrict__ imL,
                            const float* __restrict__ imR,
                            const float* __restrict__ conv_w,
                            const float* __restrict__ bn_gamma,
                            const float* __restrict__ bn_beta,
                            const float* __restrict__ bn_mean,
                            const float* __restrict__ bn_var,
                            const float* __restrict__ desc_w,
                            const float* __restrict__ desc_b,
                            float* __restrict__ xL,
                            float* __restrict__ xR)
{
    // LDS: 16-channel input patch chunk (10x34 halo) + desc stash (padded 97)
    __shared__ float patch[16 * 340];      // 21,760 B
    __shared__ float dst[256 * 97];        // 99,328 B  (total ~118 KiB)

    const int t   = threadIdx.x;
    const int xb  = blockIdx.x;            // 0..9   (32-wide tiles)
    const int yb  = blockIdx.y;            // 0..19  (8-row tiles)
    const int z   = blockIdx.z;            // 0..7
    const int b   = z & 3;
    const int img = z >> 2;
    const float* __restrict__ im = img ? imR : imL;
    float* __restrict__ xo       = img ? xR : xL;

    const int x0 = xb * 32, y0 = yb * 8;
    const int lx = t & 31,  ly = t >> 5;   // local pixel coords

    float zacc[96];
#pragma unroll
    for (int i = 0; i < 96; ++i) zacc[i] = 0.f;

    // ---- phase 1: 3x3 conv, streaming input channels in chunks of 16 ----
    for (int ch = 0; ch < 6; ++ch) {
        __syncthreads();
        // stage 16 channels of the (10 x 34) halo patch, zero-padded
        for (int e = t; e < 16 * 340; e += 256) {
            int ci_l = e / 340;
            int r    = e - ci_l * 340;
            int py   = r / 34;
            int px   = r - py * 34;
            int gy   = y0 + py - 1;
            int gx   = x0 + px - 1;
            float v = 0.f;
            if ((unsigned)gy < HH && (unsigned)gx < WW)
                v = im[((b * CH + ch * 16 + ci_l) * HH + gy) * WW + gx];
            patch[e] = v;
        }
        __syncthreads();

        for (int ci_l = 0; ci_l < 16; ++ci_l) {
            const int ci = ch * 16 + ci_l;
            float pv[9];
#pragma unroll
            for (int dy = 0; dy < 3; ++dy)
#pragma unroll
                for (int dx = 0; dx < 3; ++dx)
                    pv[dy * 3 + dx] = patch[ci_l * 340 + (ly + dy) * 34 + (lx + dx)];

            const float* __restrict__ wbase = conv_w + ci * 9; // uniform base
#pragma unroll
            for (int co = 0; co < 96; ++co) {
                const float* __restrict__ w = wbase + co * (96 * 9);
                float s = zacc[co];
                s += pv[0] * w[0]; s += pv[1] * w[1]; s += pv[2] * w[2];
                s += pv[3] * w[3]; s += pv[4] * w[4]; s += pv[5] * w[5];
                s += pv[6] * w[6]; s += pv[7] * w[7]; s += pv[8] * w[8];
                zacc[co] = s;
            }
        }
    }

    // ---- BN (inference) + LeakyReLU, fully unrolled (static zacc idx) ----
#pragma unroll
    for (int co = 0; co < 96; ++co) {
        float sc = bn_gamma[co] / sqrtf(bn_var[co] + BN_EPS);
        float sh = bn_beta[co] - bn_mean[co] * sc;
        float v  = zacc[co] * sc + sh;
        zacc[co] = (v >= 0.f) ? v : SLOPE * v;
    }

    // ---- phase 2: 1x1 desc + L2 norm. d stashed in own LDS row (no sync) --
    float ss = 0.f;
    for (int o = 0; o < 96; ++o) {          // rolled: desc_w addr uniform
        const float* __restrict__ w = desc_w + o * 96;
        float d = desc_b[o];
#pragma unroll
        for (int c2 = 0; c2 < 96; ++c2) d += zacc[c2] * w[c2];
        ss += d * d;
        dst[t * 97 + o] = d;
    }
    const float rn = 1.0f / sqrtf(ss);
    const int gy = y0 + ly, gx = x0 + lx;
    for (int o = 0; o < 96; ++o)
        xo[((b * CH + o) * HH + gy) * WW + gx] = dst[t * 97 + o] * rn;
}

// ---------------------------------------------------------------------------
// Cost volume: out[d][b][y][x] = sum_c x[b,c,y,x] * y[b,c,y,x-d], 0 for x<d.
// Block = (b, y, 64-col strip). x/y feature columns staged c-major in LDS
// (conflict-free b32 reads); each thread owns one x-column in 96 VGPRs and
// sweeps disparities d = g, g+4, ...
// ---------------------------------------------------------------------------
__launch_bounds__(256, 2)
__global__ void cost_kernel(const float* __restrict__ xF,
                            const float* __restrict__ yF,
                            float* __restrict__ out)
{
    __shared__ float xs[96 * 64];    // 24,576 B
    __shared__ float ys[96 * 112];   // 43,008 B
    const int t   = threadIdx.x;
    const int xbk = blockIdx.x;      // 0..4
    const int y   = blockIdx.y;      // 0..159
    const int b   = blockIdx.z;      // 0..3
    const int x0  = xbk * 64;

    for (int e = t; e < 96 * 64; e += 256) {
        int c = e >> 6, j = e & 63;
        xs[e] = xF[((b * CH + c) * HH + y) * WW + x0 + j];
    }
    for (int e = t; e < 96 * 112; e += 256) {
        int c = e / 112, j = e - c * 112;
        int gx = x0 - 48 + j;
        ys[e] = ((unsigned)gx < WW) ? yF[((b * CH + c) * HH + y) * WW + gx] : 0.f;
    }
    __syncthreads();

    const int col = t & 63, g = t >> 6;
    float xr[96];
#pragma unroll
    for (int c = 0; c < 96; ++c) xr[c] = xs[c * 64 + col];

    const int gx = x0 + col;
    for (int d = g; d < MAXD; d += 4) {
        const int yc = col - d + 48;         // 0..111, staged (zeros if OOB)
        float acc = 0.f;
#pragma unroll
        for (int c = 0; c < 96; ++c) acc += xr[c] * ys[c * 112 + yc];
        out[((d * BATCH + b) * HH + y) * WW + gx] = (gx - d >= 0) ? acc : 0.f;
    }
}

// ---------------------------------------------------------------------------
extern "C" void kernel_launch(void* const* d_in, const int* in_sizes, int n_in,
                              void* d_out, int out_size, void* d_ws, size_t ws_size,
                              hipStream_t stream)
{
    const float* imL      = (const float*)d_in[0];
    const float* imR      = (const float*)d_in[1];
    const float* conv_w   = (const float*)d_in[2];
    const float* bn_gamma = (const float*)d_in[3];
    const float* bn_beta  = (const float*)d_in[4];
    const float* bn_mean  = (const float*)d_in[5];
    const float* bn_var   = (const float*)d_in[6];
    const float* desc_w   = (const float*)d_in[7];
    const float* desc_b   = (const float*)d_in[8];

    // ws layout: xL features | xR features (each 4*96*160*320 f32 = 78.6 MB)
    const size_t feat_elems = (size_t)BATCH * CH * HH * WW;
    float* xL = (float*)d_ws;
    float* xR = xL + feat_elems;

    dim3 fgrid(WW / 32, HH / 8, 2 * BATCH);   // (10, 20, 8)
    feat_kernel<<<fgrid, 256, 0, stream>>>(imL, imR, conv_w, bn_gamma, bn_beta,
                                           bn_mean, bn_var, desc_w, desc_b,
                                           xL, xR);

    dim3 cgrid(WW / 64, HH, BATCH);           // (5, 160, 4)
    cost_kernel<<<cgrid, 256, 0, stream>>>(xL, xR, (float*)d_out);
}

// Round 3
// 443.112 us; speedup vs baseline: 16.6916x; 16.6916x over previous
//
#include <hip/hip_runtime.h>
#include <hip/hip_bf16.h>

#define BATCH 4
#define CH    96
#define HH    160
#define WW    320
#define MAXD  49
#define BN_EPS 1e-5f
#define SLOPE  0.01f

typedef __attribute__((ext_vector_type(8))) short bf16x8;
typedef __attribute__((ext_vector_type(4))) float f32x4;

__device__ __forceinline__ ushort f2b(float f) {
    __hip_bfloat16 h = __float2bfloat16(f);            // RNE
    return *reinterpret_cast<ushort*>(&h);
}
__device__ __forceinline__ float b2f(ushort u) {
    return __uint_as_float(((unsigned)u) << 16);       // bf16 -> f32 exact
}

// ---------------------------------------------------------------------------
// 0a: f32 NCHW image -> bf16 [img*4+b][y][x][ci] (ci innermost, for MFMA
// K-contiguity). LDS transpose tile: 96 ci x 64 x, pitch 74 (conflict-free).
// ---------------------------------------------------------------------------
__launch_bounds__(256)
__global__ void transpose_kernel(const float* __restrict__ imL,
                                 const float* __restrict__ imR,
                                 short* __restrict__ imT)
{
    __shared__ ushort tile[96 * 74];
    const int t  = threadIdx.x;
    const int x0 = blockIdx.x * 64;
    const int y  = blockIdx.y;
    const int z  = blockIdx.z;             // img*4+b
    const int b = z & 3, img = z >> 2;
    const float* __restrict__ im = img ? imR : imL;
    for (int e = t; e < 96 * 64; e += 256) {
        int ci = e >> 6, x = e & 63;       // x fastest -> coalesced reads
        tile[ci * 74 + x] = f2b(im[((b * CH + ci) * HH + y) * WW + x0 + x]);
    }
    __syncthreads();
    short* __restrict__ out = imT + (((size_t)z * HH + y) * WW + x0) * CH;
    for (int e = t; e < 64 * 96; e += 256) {
        int x = e / 96, ci = e - x * 96;   // e linear in output -> coalesced
        out[e] = (short)tile[ci * 74 + x];
    }
}

// ---------------------------------------------------------------------------
// 0b: pack conv weights (BN scale folded) and desc weights into exact
// mfma_f32_16x16x32_bf16 A-fragment order; compute BN shift vector.
// A layout: lane l holds m = l&15, k = (l>>4)*8 + j  (m89/m97-verified).
// packW idx = (((chunk*9 + tap)*6 + mf)*64 + lane)*8 + j
// ---------------------------------------------------------------------------
__launch_bounds__(256)
__global__ void pack_kernel(const float* __restrict__ conv_w,
                            const float* __restrict__ bn_gamma,
                            const float* __restrict__ bn_beta,
                            const float* __restrict__ bn_mean,
                            const float* __restrict__ bn_var,
                            const float* __restrict__ desc_w,
                            short* __restrict__ packW,   // 82944 bf16
                            short* __restrict__ packD,   // 9216 bf16
                            float* __restrict__ shv)     // 96 f32
{
    int id = blockIdx.x * 256 + threadIdx.x;
    if (id < 82944) {
        int j = id & 7, l = (id >> 3) & 63;
        int rest = id >> 9;                    // (chunk*9+tap)*6+mf
        int mf = rest % 6; int r2 = rest / 6;
        int tp = r2 % 9;  int chunk = r2 / 9;
        int co = mf * 16 + (l & 15);
        int ci = chunk * 32 + ((l >> 4) << 3) + j;
        float sc = bn_gamma[co] / sqrtf(bn_var[co] + BN_EPS);
        packW[id] = (short)f2b(conv_w[(co * 96 + ci) * 9 + tp] * sc);
    } else if (id < 92160) {
        int d = id - 82944;
        int j = d & 7, l = (d >> 3) & 63;
        int rest = d >> 9;                     // s2*6+mf
        int mf = rest % 6, s2 = rest / 6;
        int o = mf * 16 + (l & 15);
        int c = s2 * 32 + ((l >> 4) << 3) + j;
        packD[d] = (short)f2b(desc_w[o * 96 + c]);
    } else if (id < 92256) {
        int co = id - 92160;
        float sc = bn_gamma[co] / sqrtf(bn_var[co] + BN_EPS);
        shv[co] = bn_beta[co] - bn_mean[co] * sc;
    }
}

// ---------------------------------------------------------------------------
// Fused MFMA feature kernel. Block = 256 thr (4 waves); wave w owns output
// row y0+w, cols x0..x0+31. Wave tile: 96 co x 32 pix = 6 m-frags x 2 n-frags.
// Conv: K = 3 ci-chunks x 9 taps x K32. Then bias+leaky -> bf16 z in per-wave
// LDS slab -> desc MFMA (K=96) -> bias + L2-norm (shfl over lane quarters) ->
// bf16 feature store. LDS: stage buf (16.3KB) union z-slab (26.6KB).
// ---------------------------------------------------------------------------
__launch_bounds__(256, 4)
__global__ void feat_mfma_kernel(const short* __restrict__ imT,
                                 const short* __restrict__ packW,
                                 const short* __restrict__ packD,
                                 const float* __restrict__ shv,
                                 const float* __restrict__ desc_b,
                                 short* __restrict__ feat)
{
    __shared__ short lds[13312];   // union: stage 6*34*40=8160 / z 4*32*104=13312

    const int tid  = threadIdx.x;
    const int lane = tid & 63, w = tid >> 6;
    const int q = lane >> 4, l15 = lane & 15;
    const int x0 = blockIdx.x * 32, y0 = blockIdx.y * 4;
    const int z  = blockIdx.z;                     // img*4+b

    const f32x4 fz = {0.f, 0.f, 0.f, 0.f};
    f32x4 acc[6][2];
#pragma unroll
    for (int mf = 0; mf < 6; ++mf) { acc[mf][0] = fz; acc[mf][1] = fz; }

    const bf16x8* __restrict__ wv = (const bf16x8*)packW;
    const size_t imbase = (size_t)z * HH * WW * CH;

    for (int chunk = 0; chunk < 3; ++chunk) {
        __syncthreads();                            // prior chunk reads done
        for (int e = tid; e < 816; e += 256) {      // 6r x 34c x 4 groups
            int r = e / 136, rem = e - r * 136;
            int c = rem >> 2, g = rem & 3;
            int gy = y0 - 1 + r, gx = x0 - 1 + c;
            bf16x8 v = {0, 0, 0, 0, 0, 0, 0, 0};
            if ((unsigned)gy < HH && (unsigned)gx < WW)
                v = *(const bf16x8*)(imT + imbase + ((size_t)gy * WW + gx) * CH
                                     + chunk * 32 + g * 8);
            *(bf16x8*)&lds[(r * 34 + c) * 40 + g * 8] = v;   // pitch 40 -> 80B
        }
        __syncthreads();
        for (int tp = 0; tp < 9; ++tp) {
            int dy = tp / 3, dx = tp - dy * 3;
            int cell = (w + dy) * 34 + l15 + dx;
            bf16x8 B0 = *(const bf16x8*)&lds[cell * 40 + q * 8];         // p=0
            bf16x8 B1 = *(const bf16x8*)&lds[(cell + 16) * 40 + q * 8];  // p=1
            const bf16x8* wf = wv + ((chunk * 9 + tp) * 6) * 64 + lane;
#pragma unroll
            for (int mf = 0; mf < 6; ++mf) {
                bf16x8 A = wf[mf * 64];
                acc[mf][0] = __builtin_amdgcn_mfma_f32_16x16x32_bf16(A, B0, acc[mf][0], 0, 0, 0);
                acc[mf][1] = __builtin_amdgcn_mfma_f32_16x16x32_bf16(A, B1, acc[mf][1], 0, 0, 0);
            }
        }
    }

    __syncthreads();            // all conv LDS reads done -> reuse lds as z-slab
    short* zs = lds + w * (32 * 104);       // per-wave slab, no cross-wave sync

    // BN shift + LeakyReLU + bf16, write z[pix][co] (C/D row = q*4+r)
#pragma unroll
    for (int mf = 0; mf < 6; ++mf)
#pragma unroll
        for (int p = 0; p < 2; ++p) {
            int pix = p * 16 + l15;
#pragma unroll
            for (int r = 0; r < 4; r += 2) {
                int co = mf * 16 + q * 4 + r;
                float z0 = acc[mf][p][r]     + shv[co];
                float z1 = acc[mf][p][r + 1] + shv[co + 1];
                z0 = z0 >= 0.f ? z0 : SLOPE * z0;
                z1 = z1 >= 0.f ? z1 : SLOPE * z1;
                unsigned pk = (unsigned)f2b(z0) | ((unsigned)f2b(z1) << 16);
                *(unsigned*)&zs[pix * 104 + co] = pk;
            }
        }

    // desc 1x1 via MFMA, K = 96 (3 steps of 32)
    f32x4 dacc[6][2];
#pragma unroll
    for (int mf = 0; mf < 6; ++mf) { dacc[mf][0] = fz; dacc[mf][1] = fz; }
    const bf16x8* __restrict__ dv = (const bf16x8*)packD;
#pragma unroll
    for (int s2 = 0; s2 < 3; ++s2) {
        bf16x8 B0 = *(const bf16x8*)&zs[l15 * 104        + s2 * 32 + q * 8];
        bf16x8 B1 = *(const bf16x8*)&zs[(16 + l15) * 104 + s2 * 32 + q * 8];
        const bf16x8* df = dv + (s2 * 6) * 64 + lane;
#pragma unroll
        for (int mf = 0; mf < 6; ++mf) {
            bf16x8 A = df[mf * 64];
            dacc[mf][0] = __builtin_amdgcn_mfma_f32_16x16x32_bf16(A, B0, dacc[mf][0], 0, 0, 0);
            dacc[mf][1] = __builtin_amdgcn_mfma_f32_16x16x32_bf16(A, B1, dacc[mf][1], 0, 0, 0);
        }
    }

    // desc bias + L2 norm (reduce across the 4 lane-quarters) + store bf16
    float ss0 = 0.f, ss1 = 0.f;
#pragma unroll
    for (int mf = 0; mf < 6; ++mf)
#pragma unroll
        for (int r = 0; r < 4; ++r) {
            int o = mf * 16 + q * 4 + r;
            float bias = desc_b[o];
            float d0 = dacc[mf][0][r] + bias;
            float d1 = dacc[mf][1][r] + bias;
            dacc[mf][0][r] = d0; dacc[mf][1][r] = d1;
            ss0 += d0 * d0; ss1 += d1 * d1;
        }
    ss0 += __shfl_xor(ss0, 16, 64); ss0 += __shfl_xor(ss0, 32, 64);
    ss1 += __shfl_xor(ss1, 16, 64); ss1 += __shfl_xor(ss1, 32, 64);
    const float rn0 = 1.f / sqrtf(ss0), rn1 = 1.f / sqrtf(ss1);

    const int gy = y0 + w;
    short* __restrict__ fo = feat + (size_t)z * CH * HH * WW;
#pragma unroll
    for (int mf = 0; mf < 6; ++mf)
#pragma unroll
        for (int r = 0; r < 4; ++r) {
            int o = mf * 16 + q * 4 + r;
            size_t base = ((size_t)o * HH + gy) * WW + x0 + l15;
            fo[base]      = (short)f2b(dacc[mf][0][r] * rn0);
            fo[base + 16] = (short)f2b(dacc[mf][1][r] * rn1);
        }
}

// ---------------------------------------------------------------------------
// Cost volume on bf16 features; LDS staged raw u16 (33.5 KB -> 4 blocks/CU).
// ---------------------------------------------------------------------------
__launch_bounds__(256, 4)
__global__ void cost_kernel(const short* __restrict__ xF,
                            const short* __restrict__ yF,
                            float* __restrict__ out)
{
    __shared__ ushort xs[96 * 64];
    __shared__ ushort ys[96 * 112];
    const int t  = threadIdx.x;
    const int x0 = blockIdx.x * 64;
    const int y  = blockIdx.y, b = blockIdx.z;

    for (int e = t; e < 96 * 64; e += 256) {
        int c = e >> 6, j = e & 63;
        xs[e] = (ushort)xF[((b * CH + c) * HH + y) * WW + x0 + j];
    }
    for (int e = t; e < 96 * 112; e += 256) {
        int c = e / 112, j = e - c * 112;
        int gx = x0 - 48 + j;
        ys[e] = ((unsigned)gx < WW) ? (ushort)yF[((b * CH + c) * HH + y) * WW + gx]
                                    : (ushort)0;
    }
    __syncthreads();

    const int col = t & 63, g = t >> 6;
    float xr[96];
#pragma unroll
    for (int c = 0; c < 96; ++c) xr[c] = b2f(xs[c * 64 + col]);

    const int gx = x0 + col;
    for (int d = g; d < MAXD; d += 4) {
        const int yc = col - d + 48;
        float acc = 0.f;
#pragma unroll
        for (int c = 0; c < 96; ++c) acc += xr[c] * b2f(ys[c * 112 + yc]);
        out[(((size_t)d * BATCH + b) * HH + y) * WW + gx] = (gx - d >= 0) ? acc : 0.f;
    }
}

// ---------------------------------------------------------------------------
extern "C" void kernel_launch(void* const* d_in, const int* in_sizes, int n_in,
                              void* d_out, int out_size, void* d_ws, size_t ws_size,
                              hipStream_t stream)
{
    const float* imL      = (const float*)d_in[0];
    const float* imR      = (const float*)d_in[1];
    const float* conv_w   = (const float*)d_in[2];
    const float* bn_gamma = (const float*)d_in[3];
    const float* bn_beta  = (const float*)d_in[4];
    const float* bn_mean  = (const float*)d_in[5];
    const float* bn_var   = (const float*)d_in[6];
    const float* desc_w   = (const float*)d_in[7];
    const float* desc_b   = (const float*)d_in[8];

    // d_ws: imT bf16 (78.6 MB) | features bf16 (78.6 MB)  == round-0-proven size
    const size_t half = (size_t)8 * HH * WW * CH;          // elems per region
    short* imT  = (short*)d_ws;
    short* feat = (short*)d_ws + half;

    // pack buffers live in the first 185 KB of d_out; feat kernel consumes
    // them BEFORE cost_kernel overwrites all of d_out (same-stream ordering).
    short* packW = (short*)d_out;                          // 165,888 B
    short* packD = (short*)((char*)d_out + 165888);        //  18,432 B
    float* shv   = (float*)((char*)d_out + 184320);        //     384 B

    dim3 tgrid(WW / 64, HH, 2 * BATCH);                    // (5,160,8)
    transpose_kernel<<<tgrid, 256, 0, stream>>>(imL, imR, imT);

    pack_kernel<<<361, 256, 0, stream>>>(conv_w, bn_gamma, bn_beta, bn_mean,
                                         bn_var, desc_w, packW, packD, shv);

    dim3 fgrid(WW / 32, HH / 4, 2 * BATCH);                // (10,40,8)
    feat_mfma_kernel<<<fgrid, 256, 0, stream>>>(imT, packW, packD, shv,
                                                desc_b, feat);

    const size_t img_elems = (size_t)BATCH * CH * HH * WW;
    dim3 cgrid(WW / 64, HH, BATCH);                        // (5,160,4)
    cost_kernel<<<cgrid, 256, 0, stream>>>(feat, feat + img_elems, (float*)d_out);
}

// Round 5
// 395.398 us; speedup vs baseline: 18.7058x; 1.1207x over previous
//
#include <hip/hip_runtime.h>
#include <hip/hip_bf16.h>

#define BATCH 4
#define CH    96
#define HH    160
#define WW    320
#define MAXD  49
#define BN_EPS 1e-5f
#define SLOPE  0.01f

typedef __attribute__((ext_vector_type(8))) short bf16x8;
typedef __attribute__((ext_vector_type(4))) float f32x4;

__device__ __forceinline__ ushort f2b(float f) {
    __hip_bfloat16 h = __float2bfloat16(f);            // RNE
    return *reinterpret_cast<ushort*>(&h);
}

// ---------------------------------------------------------------------------
// 0a: f32 NCHW image -> bf16 [img*4+b][y][x][ci] (ci innermost). Unchanged.
// ---------------------------------------------------------------------------
__launch_bounds__(256)
__global__ void transpose_kernel(const float* __restrict__ imL,
                                 const float* __restrict__ imR,
                                 short* __restrict__ imT)
{
    __shared__ ushort tile[96 * 74];
    const int t  = threadIdx.x;
    const int x0 = blockIdx.x * 64;
    const int y  = blockIdx.y;
    const int z  = blockIdx.z;             // img*4+b
    const int b = z & 3, img = z >> 2;
    const float* __restrict__ im = img ? imR : imL;
    for (int e = t; e < 96 * 64; e += 256) {
        int ci = e >> 6, x = e & 63;
        tile[ci * 74 + x] = f2b(im[((b * CH + ci) * HH + y) * WW + x0 + x]);
    }
    __syncthreads();
    short* __restrict__ out = imT + (((size_t)z * HH + y) * WW + x0) * CH;
    for (int e = t; e < 64 * 96; e += 256) {
        int x = e / 96, ci = e - x * 96;
        out[e] = (short)tile[ci * 74 + x];
    }
}

// ---------------------------------------------------------------------------
// 0b: pack conv weights (BN scale folded) + desc weights into exact
// mfma_f32_16x16x32_bf16 A-fragment order (lane l: m=l&15, k=(l>>4)*8+j).
// ---------------------------------------------------------------------------
__launch_bounds__(256)
__global__ void pack_kernel(const float* __restrict__ conv_w,
                            const float* __restrict__ bn_gamma,
                            const float* __restrict__ bn_beta,
                            const float* __restrict__ bn_mean,
                            const float* __restrict__ bn_var,
                            const float* __restrict__ desc_w,
                            short* __restrict__ packW,   // 82944 bf16
                            short* __restrict__ packD,   // 9216 bf16
                            float* __restrict__ shv)     // 96 f32
{
    int id = blockIdx.x * 256 + threadIdx.x;
    if (id < 82944) {
        int j = id & 7, l = (id >> 3) & 63;
        int rest = id >> 9;                    // (chunk*9+tap)*6+mf
        int mf = rest % 6; int r2 = rest / 6;
        int tp = r2 % 9;  int chunk = r2 / 9;
        int co = mf * 16 + (l & 15);
        int ci = chunk * 32 + ((l >> 4) << 3) + j;
        float sc = bn_gamma[co] / sqrtf(bn_var[co] + BN_EPS);
        packW[id] = (short)f2b(conv_w[(co * 96 + ci) * 9 + tp] * sc);
    } else if (id < 92160) {
        int d = id - 82944;
        int j = d & 7, l = (d >> 3) & 63;
        int rest = d >> 9;                     // s2*6+mf
        int mf = rest % 6, s2 = rest / 6;
        int o = mf * 16 + (l & 15);
        int c = s2 * 32 + ((l >> 4) << 3) + j;
        packD[d] = (short)f2b(desc_w[o * 96 + c]);
    } else if (id < 92256) {
        int co = id - 92160;
        float sc = bn_gamma[co] / sqrtf(bn_var[co] + BN_EPS);
        shv[co] = bn_beta[co] - bn_mean[co] * sc;
    }
}

// ---------------------------------------------------------------------------
// Fused MFMA feature kernel (Round-4 design, now actually validated).
// 4 waves; wave w owns row y0+w, cols x0..x0+31. Double-buffered reg staging
// (T14), one barrier per chunk. z-slab: 16B-chunk XOR swizzle (chunk^(pix&15))
// -> conflict-free writes and desc b128 reads. Output [z][y][x][c] bf16 via
// slab repack -> coalesced b128 stores.
// ---------------------------------------------------------------------------
__launch_bounds__(256, 3)
__global__ void feat_mfma_kernel(const short* __restrict__ imT,
                                 const short* __restrict__ packW,
                                 const short* __restrict__ packD,
                                 const float* __restrict__ shv,
                                 const float* __restrict__ desc_b,
                                 short* __restrict__ feat)
{
    // union: stage bufA [0,8160) bufB [8160,16320)  /  z-slab [0,16384)
    __shared__ __align__(16) short lds[16384];          // 32 KiB

    const int tid  = threadIdx.x;
    const int lane = tid & 63, w = tid >> 6;
    const int q = lane >> 4, l15 = lane & 15;
    const int x0 = blockIdx.x * 32, y0 = blockIdx.y * 4;
    const int z  = blockIdx.z;                          // img*4+b
    const size_t imbase = (size_t)z * HH * WW * CH;

    const bf16x8 vz8 = {0, 0, 0, 0, 0, 0, 0, 0};
    const f32x4  fz  = {0.f, 0.f, 0.f, 0.f};

    f32x4 acc[6][2];
#pragma unroll
    for (int mf = 0; mf < 6; ++mf) { acc[mf][0] = fz; acc[mf][1] = fz; }

    const bf16x8* __restrict__ wv = (const bf16x8*)packW;
    bf16x8 sv[4];

#define STAGE_LOAD(chunk)                                                      \
    {                                                                          \
        _Pragma("unroll")                                                      \
        for (int k = 0; k < 4; ++k) {                                          \
            int e = tid + k * 256;                                             \
            bf16x8 v = vz8;                                                    \
            if (e < 816) {                                                     \
                int r = e / 136, rem = e - r * 136;                            \
                int cc = rem >> 2, g = rem & 3;                                \
                int gy = y0 - 1 + r, gx = x0 - 1 + cc;                         \
                if ((unsigned)gy < HH && (unsigned)gx < WW)                    \
                    v = *(const bf16x8*)(imT + imbase +                        \
                        ((size_t)gy * WW + gx) * CH + (chunk) * 32 + g * 8);   \
            }                                                                  \
            sv[k] = v;                                                         \
        }                                                                      \
    }

#define STAGE_WRITE(bufofs)                                                    \
    {                                                                          \
        _Pragma("unroll")                                                      \
        for (int k = 0; k < 4; ++k) {                                          \
            int e = tid + k * 256;                                             \
            if (e < 816) {                                                     \
                int r = e / 136, rem = e - r * 136;                            \
                int cc = rem >> 2, g = rem & 3;                                \
                *(bf16x8*)&lds[(bufofs) + (r * 34 + cc) * 40 + g * 8] = sv[k]; \
            }                                                                  \
        }                                                                      \
    }

    STAGE_LOAD(0);
    STAGE_WRITE(0);
    __syncthreads();

#pragma unroll
    for (int c = 0; c < 3; ++c) {
        if (c < 2) STAGE_LOAD(c + 1);                  // loads fly over MFMAs
        const int bo = (c & 1) ? 8160 : 0;
        for (int tp = 0; tp < 9; ++tp) {
            int dy = tp / 3, dx = tp - dy * 3;
            int cell = (w + dy) * 34 + l15 + dx;
            bf16x8 B0 = *(const bf16x8*)&lds[bo + cell * 40 + q * 8];
            bf16x8 B1 = *(const bf16x8*)&lds[bo + (cell + 16) * 40 + q * 8];
            const bf16x8* wf = wv + ((c * 9 + tp) * 6) * 64 + lane;
#pragma unroll
            for (int mf = 0; mf < 6; ++mf) {
                bf16x8 A = wf[mf * 64];
                acc[mf][0] = __builtin_amdgcn_mfma_f32_16x16x32_bf16(A, B0, acc[mf][0], 0, 0, 0);
                acc[mf][1] = __builtin_amdgcn_mfma_f32_16x16x32_bf16(A, B1, acc[mf][1], 0, 0, 0);
            }
        }
        if (c < 2) {
            STAGE_WRITE((c & 1) ? 0 : 8160);
            __syncthreads();
        }
    }
    __syncthreads();          // stage-buffer readers done -> reuse as z-slab

    short* zs = lds + w * 4096;             // per-wave 32pix x 128short slab

    // BN shift + LeakyReLU -> bf16 z, XOR-swizzled writes (conflict-free)
#pragma unroll
    for (int mf = 0; mf < 6; ++mf)
#pragma unroll
        for (int p = 0; p < 2; ++p) {
            int pix = p * 16 + l15;
#pragma unroll
            for (int r = 0; r < 4; r += 2) {
                int co = mf * 16 + q * 4 + r;
                float z0 = acc[mf][p][r]     + shv[co];
                float z1 = acc[mf][p][r + 1] + shv[co + 1];
                z0 = z0 >= 0.f ? z0 : SLOPE * z0;
                z1 = z1 >= 0.f ? z1 : SLOPE * z1;
                unsigned pk = (unsigned)f2b(z0) | ((unsigned)f2b(z1) << 16);
                int c8 = mf * 2 + (q >> 1);
                int zi = pix * 128 + ((c8 ^ l15) * 8) + (q & 1) * 4 + r;
                *(unsigned*)&zs[zi] = pk;
            }
        }

    // desc 1x1 via MFMA, K=96 (XOR-swizzled b128 reads, conflict-free)
    f32x4 dacc[6][2];
#pragma unroll
    for (int mf = 0; mf < 6; ++mf) { dacc[mf][0] = fz; dacc[mf][1] = fz; }
    const bf16x8* __restrict__ dv = (const bf16x8*)packD;
#pragma unroll
    for (int s2 = 0; s2 < 3; ++s2) {
        int ch16 = s2 * 4 + q;
        bf16x8 B0 = *(const bf16x8*)&zs[l15 * 128        + ((ch16 ^ l15) * 8)];
        bf16x8 B1 = *(const bf16x8*)&zs[(16 + l15) * 128 + ((ch16 ^ l15) * 8)];
        const bf16x8* df = dv + (s2 * 6) * 64 + lane;
#pragma unroll
        for (int mf = 0; mf < 6; ++mf) {
            bf16x8 A = df[mf * 64];
            dacc[mf][0] = __builtin_amdgcn_mfma_f32_16x16x32_bf16(A, B0, dacc[mf][0], 0, 0, 0);
            dacc[mf][1] = __builtin_amdgcn_mfma_f32_16x16x32_bf16(A, B1, dacc[mf][1], 0, 0, 0);
        }
    }

    // bias + L2 norm (reduce over lane quarters)
    float ss0 = 0.f, ss1 = 0.f;
#pragma unroll
    for (int mf = 0; mf < 6; ++mf)
#pragma unroll
        for (int r = 0; r < 4; ++r) {
            int o = mf * 16 + q * 4 + r;
            float bias = desc_b[o];
            float d0 = dacc[mf][0][r] + bias;
            float d1 = dacc[mf][1][r] + bias;
            dacc[mf][0][r] = d0; dacc[mf][1][r] = d1;
            ss0 += d0 * d0; ss1 += d1 * d1;
        }
    ss0 += __shfl_xor(ss0, 16, 64); ss0 += __shfl_xor(ss0, 32, 64);
    ss1 += __shfl_xor(ss1, 16, 64); ss1 += __shfl_xor(ss1, 32, 64);
    const float rn0 = 1.f / sqrtf(ss0), rn1 = 1.f / sqrtf(ss1);

    // normalized bf16 back into the slab (same swizzle), same-wave ordering
#pragma unroll
    for (int mf = 0; mf < 6; ++mf)
#pragma unroll
        for (int p = 0; p < 2; ++p) {
            int pix = p * 16 + l15;
            float rn = p ? rn1 : rn0;
#pragma unroll
            for (int r = 0; r < 4; r += 2) {
                float d0 = dacc[mf][p][r]     * rn;
                float d1 = dacc[mf][p][r + 1] * rn;
                unsigned pk = (unsigned)f2b(d0) | ((unsigned)f2b(d1) << 16);
                int c8 = mf * 2 + (q >> 1);
                int zi = pix * 128 + ((c8 ^ l15) * 8) + (q & 1) * 4 + r;
                *(unsigned*)&zs[zi] = pk;
            }
        }

    // cooperative coalesced store: wave slab -> feat[z][y0+w][x0..x0+32][c]
    short* __restrict__ fo = feat + (((size_t)z * HH + y0 + w) * WW + x0) * CH;
#pragma unroll
    for (int it = 0; it < 6; ++it) {
        int cid = it * 64 + lane;              // 384 chunks = 32pix x 12
        int pix = cid / 12, c16 = cid - pix * 12;
        bf16x8 v = *(const bf16x8*)&zs[pix * 128 + ((c16 ^ (pix & 15)) * 8)];
        *(bf16x8*)&fo[pix * 96 + c16 * 8] = v;
    }
#undef STAGE_LOAD
#undef STAGE_WRITE
}

// ---------------------------------------------------------------------------
// Cost volume via MFMA. Block = one (b,y) row, 4 waves; wave w owns x-tiles
// T0=5w..5w+4. Y row staged [col = x'+48][c] bf16 in LDS, PITCH = 13 chunks
// (104 shorts, 208 B): lane stride = 52 dwords == 20 mod 32 -> full 32-bank
// coverage per 8 lanes (2-way free). Chunk 12 of each col is a pad slot,
// filled with a duplicate load, never read (global_load_lds dest stays
// linear; the col/ch split lives in the per-lane SOURCE address).
// Cols 0..47 zero = left pad -> exact zeros for x<d.
// Each 16x16 C-tile: lane (q,l15), reg r: x = 16T+q*4+r, d = 48-16u+q*4+r-l15.
// ---------------------------------------------------------------------------
#define NCOL 368
#define YPITCH 104           // shorts per col = 13 chunks of 8
__launch_bounds__(256, 2)
__global__ void cost_mfma_kernel(const short* __restrict__ xF,
                                 const short* __restrict__ yF,
                                 float* __restrict__ out)
{
    __shared__ __align__(16) short ylds[NCOL * YPITCH];   // 76,544 B
    const int tid = threadIdx.x, lane = tid & 63, w = tid >> 6;
    const int q = lane >> 4, l15 = lane & 15;
    const int y = blockIdx.x, b = blockIdx.y;

    const bf16x8 vz8 = {0, 0, 0, 0, 0, 0, 0, 0};
    const f32x4  fz  = {0.f, 0.f, 0.f, 0.f};

    // left zero-pad: cols 0..47 -> chunks [0, 624)
    for (int e = tid; e < 624; e += 256)
        *(bf16x8*)&ylds[e * 8] = vz8;

    // valid region: chunks [624, 4784) = 65 wave-loads of 64 chunks.
    // Y features are image R = z-slab (4+b) of the feature buffer.
    const size_t ybase = ((size_t)(4 + b) * HH + y) * WW * CH;
    for (int wl = w; wl < 65; wl += 4) {
        int cb  = 624 + wl * 64;                       // wave-uniform
        int cid = cb + lane;
        int col = cid / 13, ch = cid - col * 13;
        if (ch == 12) ch = 0;                          // pad slot: dup load
        const short* gp = yF + ybase + (size_t)(col - 48) * CH + ch * 8;
        __builtin_amdgcn_global_load_lds(
            (const __attribute__((address_space(1))) unsigned int*)gp,
            (__attribute__((address_space(3))) unsigned int*)&ylds[(size_t)cb * 8],
            16, 0, 0);
    }
    __syncthreads();

    // X features are image L = z-slab b.
    const size_t xbase = ((size_t)b * HH + y) * WW * CH;
    const int T0 = w * 5;

    bf16x8 Bc[4][3];                                   // rolling x'-tile cache
#pragma unroll
    for (int u = 0; u < 4; ++u)
#pragma unroll
        for (int s2 = 0; s2 < 3; ++s2)
            Bc[u][s2] = *(const bf16x8*)&ylds[(16 * (T0 + u) + l15) * YPITCH
                                              + (s2 * 4 + q) * 8];

#pragma unroll
    for (int tl = 0; tl < 5; ++tl) {
        bf16x8 A[3];
#pragma unroll
        for (int s2 = 0; s2 < 3; ++s2)
            A[s2] = *(const bf16x8*)(xF + xbase +
                     (size_t)(16 * (T0 + tl) + l15) * 96 + s2 * 32 + q * 8);
        if (tl > 0) {
#pragma unroll
            for (int s2 = 0; s2 < 3; ++s2)
                Bc[(tl + 3) & 3][s2] = *(const bf16x8*)&ylds[
                    (16 * (T0 + tl + 3) + l15) * YPITCH + (s2 * 4 + q) * 8];
        }
        f32x4 acc[4] = {fz, fz, fz, fz};
#pragma unroll
        for (int u = 0; u < 4; ++u)
#pragma unroll
            for (int s2 = 0; s2 < 3; ++s2)
                acc[u] = __builtin_amdgcn_mfma_f32_16x16x32_bf16(
                    A[s2], Bc[(tl + u) & 3][s2], acc[u], 0, 0, 0);

        const int x = 16 * (T0 + tl) + q * 4;
#pragma unroll
        for (int u = 0; u < 4; ++u)
#pragma unroll
            for (int r = 0; r < 4; ++r) {
                int d = 48 - 16 * u + q * 4 + r - l15;
                if (0 <= d && d <= 48)
                    out[((size_t)(d * BATCH + b) * HH + y) * WW + x + r] = acc[u][r];
            }
    }
}

// ---------------------------------------------------------------------------
extern "C" void kernel_launch(void* const* d_in, const int* in_sizes, int n_in,
                              void* d_out, int out_size, void* d_ws, size_t ws_size,
                              hipStream_t stream)
{
    const float* imL      = (const float*)d_in[0];
    const float* imR      = (const float*)d_in[1];
    const float* conv_w   = (const float*)d_in[2];
    const float* bn_gamma = (const float*)d_in[3];
    const float* bn_beta  = (const float*)d_in[4];
    const float* bn_mean  = (const float*)d_in[5];
    const float* bn_var   = (const float*)d_in[6];
    const float* desc_w   = (const float*)d_in[7];
    const float* desc_b   = (const float*)d_in[8];

    // d_ws: imT bf16 [8][160][320][96] | feat bf16 [8][160][320][96]
    const size_t half = (size_t)8 * HH * WW * CH;
    short* imT  = (short*)d_ws;
    short* feat = (short*)d_ws + half;

    // pack buffers in the head of d_out; consumed by feat_mfma BEFORE
    // cost_mfma overwrites d_out (same-stream ordering).
    short* packW = (short*)d_out;                      // 165,888 B
    short* packD = (short*)((char*)d_out + 165888);    //  18,432 B
    float* shv   = (float*)((char*)d_out + 184320);    //     384 B

    dim3 tgrid(WW / 64, HH, 2 * BATCH);                // (5,160,8)
    transpose_kernel<<<tgrid, 256, 0, stream>>>(imL, imR, imT);

    pack_kernel<<<361, 256, 0, stream>>>(conv_w, bn_gamma, bn_beta, bn_mean,
                                         bn_var, desc_w, packW, packD, shv);

    dim3 fgrid(WW / 32, HH / 4, 2 * BATCH);            // (10,40,8)
    feat_mfma_kernel<<<fgrid, 256, 0, stream>>>(imT, packW, packD, shv,
                                                desc_b, feat);

    // BUGFIX (R4): pass the feature base for BOTH X and Y; the kernel itself
    // selects z = b (image L) and z = 4+b (image R). Round 4 applied the
    // image-R offset twice -> Y read 0xAA poison -> all-zero cost volume.
    dim3 cgrid(HH, BATCH);                             // (160,4)
    cost_mfma_kernel<<<cgrid, 256, 0, stream>>>(feat, feat, (float*)d_out);
}

// Round 6
// 380.164 us; speedup vs baseline: 19.4554x; 1.0401x over previous
//
#include <hip/hip_runtime.h>
#include <hip/hip_bf16.h>

#define BATCH 4
#define CH    96
#define HH    160
#define WW    320
#define MAXD  49
#define BN_EPS 1e-5f
#define SLOPE  0.01f

typedef __attribute__((ext_vector_type(8))) short bf16x8;
typedef __attribute__((ext_vector_type(4))) float f32x4;

__device__ __forceinline__ ushort f2b(float f) {
    __hip_bfloat16 h = __float2bfloat16(f);            // RNE
    return *reinterpret_cast<ushort*>(&h);
}

// ---------------------------------------------------------------------------
// 0a: f32 NCHW image -> bf16 [img*4+b][y][x][ci] (ci innermost). Unchanged.
// ---------------------------------------------------------------------------
__launch_bounds__(256)
__global__ void transpose_kernel(const float* __restrict__ imL,
                                 const float* __restrict__ imR,
                                 short* __restrict__ imT)
{
    __shared__ ushort tile[96 * 74];
    const int t  = threadIdx.x;
    const int x0 = blockIdx.x * 64;
    const int y  = blockIdx.y;
    const int z  = blockIdx.z;             // img*4+b
    const int b = z & 3, img = z >> 2;
    const float* __restrict__ im = img ? imR : imL;
    for (int e = t; e < 96 * 64; e += 256) {
        int ci = e >> 6, x = e & 63;
        tile[ci * 74 + x] = f2b(im[((b * CH + ci) * HH + y) * WW + x0 + x]);
    }
    __syncthreads();
    short* __restrict__ out = imT + (((size_t)z * HH + y) * WW + x0) * CH;
    for (int e = t; e < 64 * 96; e += 256) {
        int x = e / 96, ci = e - x * 96;
        out[e] = (short)tile[ci * 74 + x];
    }
}

// ---------------------------------------------------------------------------
// 0b: pack conv weights (BN scale folded) + desc weights into exact
// mfma_f32_16x16x32_bf16 A-fragment order (lane l: m=l&15, k=(l>>4)*8+j).
// ---------------------------------------------------------------------------
__launch_bounds__(256)
__global__ void pack_kernel(const float* __restrict__ conv_w,
                            const float* __restrict__ bn_gamma,
                            const float* __restrict__ bn_beta,
                            const float* __restrict__ bn_mean,
                            const float* __restrict__ bn_var,
                            const float* __restrict__ desc_w,
                            short* __restrict__ packW,   // 82944 bf16
                            short* __restrict__ packD,   // 9216 bf16
                            float* __restrict__ shv)     // 96 f32
{
    int id = blockIdx.x * 256 + threadIdx.x;
    if (id < 82944) {
        int j = id & 7, l = (id >> 3) & 63;
        int rest = id >> 9;                    // (chunk*9+tap)*6+mf
        int mf = rest % 6; int r2 = rest / 6;
        int tp = r2 % 9;  int chunk = r2 / 9;
        int co = mf * 16 + (l & 15);
        int ci = chunk * 32 + ((l >> 4) << 3) + j;
        float sc = bn_gamma[co] / sqrtf(bn_var[co] + BN_EPS);
        packW[id] = (short)f2b(conv_w[(co * 96 + ci) * 9 + tp] * sc);
    } else if (id < 92160) {
        int d = id - 82944;
        int j = d & 7, l = (d >> 3) & 63;
        int rest = d >> 9;                     // s2*6+mf
        int mf = rest % 6, s2 = rest / 6;
        int o = mf * 16 + (l & 15);
        int c = s2 * 32 + ((l >> 4) << 3) + j;
        packD[d] = (short)f2b(desc_w[o * 96 + c]);
    } else if (id < 92256) {
        int co = id - 92160;
        float sc = bn_gamma[co] / sqrtf(bn_var[co] + BN_EPS);
        shv[co] = bn_beta[co] - bn_mean[co] * sc;
    }
}

// ---------------------------------------------------------------------------
// Fused MFMA feature kernel. R6 change: tap loop fully unrolled so the 54
// global weight-fragment loads per chunk pipeline across taps instead of
// stalling each tap on ~200cy L2 latency.
// ---------------------------------------------------------------------------
__launch_bounds__(256, 3)
__global__ void feat_mfma_kernel(const short* __restrict__ imT,
                                 const short* __restrict__ packW,
                                 const short* __restrict__ packD,
                                 const float* __restrict__ shv,
                                 const float* __restrict__ desc_b,
                                 short* __restrict__ feat)
{
    // union: stage bufA [0,8160) bufB [8160,16320)  /  z-slab [0,16384)
    __shared__ __align__(16) short lds[16384];          // 32 KiB

    const int tid  = threadIdx.x;
    const int lane = tid & 63, w = tid >> 6;
    const int q = lane >> 4, l15 = lane & 15;
    const int x0 = blockIdx.x * 32, y0 = blockIdx.y * 4;
    const int z  = blockIdx.z;                          // img*4+b
    const size_t imbase = (size_t)z * HH * WW * CH;

    const bf16x8 vz8 = {0, 0, 0, 0, 0, 0, 0, 0};
    const f32x4  fz  = {0.f, 0.f, 0.f, 0.f};

    f32x4 acc[6][2];
#pragma unroll
    for (int mf = 0; mf < 6; ++mf) { acc[mf][0] = fz; acc[mf][1] = fz; }

    const bf16x8* __restrict__ wv = (const bf16x8*)packW;
    bf16x8 sv[4];

#define STAGE_LOAD(chunk)                                                      \
    {                                                                          \
        _Pragma("unroll")                                                      \
        for (int k = 0; k < 4; ++k) {                                          \
            int e = tid + k * 256;                                             \
            bf16x8 v = vz8;                                                    \
            if (e < 816) {                                                     \
                int r = e / 136, rem = e - r * 136;                            \
                int cc = rem >> 2, g = rem & 3;                                \
                int gy = y0 - 1 + r, gx = x0 - 1 + cc;                         \
                if ((unsigned)gy < HH && (unsigned)gx < WW)                    \
                    v = *(const bf16x8*)(imT + imbase +                        \
                        ((size_t)gy * WW + gx) * CH + (chunk) * 32 + g * 8);   \
            }                                                                  \
            sv[k] = v;                                                         \
        }                                                                      \
    }

#define STAGE_WRITE(bufofs)                                                    \
    {                                                                          \
        _Pragma("unroll")                                                      \
        for (int k = 0; k < 4; ++k) {                                          \
            int e = tid + k * 256;                                             \
            if (e < 816) {                                                     \
                int r = e / 136, rem = e - r * 136;                            \
                int cc = rem >> 2, g = rem & 3;                                \
                *(bf16x8*)&lds[(bufofs) + (r * 34 + cc) * 40 + g * 8] = sv[k]; \
            }                                                                  \
        }                                                                      \
    }

    STAGE_LOAD(0);
    STAGE_WRITE(0);
    __syncthreads();

#pragma unroll
    for (int c = 0; c < 3; ++c) {
        if (c < 2) STAGE_LOAD(c + 1);                  // loads fly over MFMAs
        const int bo = (c & 1) ? 8160 : 0;
#pragma unroll
        for (int tp = 0; tp < 9; ++tp) {
            int dy = tp / 3, dx = tp - dy * 3;
            int cell = (w + dy) * 34 + l15 + dx;
            bf16x8 B0 = *(const bf16x8*)&lds[bo + cell * 40 + q * 8];
            bf16x8 B1 = *(const bf16x8*)&lds[bo + (cell + 16) * 40 + q * 8];
            const bf16x8* wf = wv + ((c * 9 + tp) * 6) * 64 + lane;
#pragma unroll
            for (int mf = 0; mf < 6; ++mf) {
                bf16x8 A = wf[mf * 64];
                acc[mf][0] = __builtin_amdgcn_mfma_f32_16x16x32_bf16(A, B0, acc[mf][0], 0, 0, 0);
                acc[mf][1] = __builtin_amdgcn_mfma_f32_16x16x32_bf16(A, B1, acc[mf][1], 0, 0, 0);
            }
        }
        if (c < 2) {
            STAGE_WRITE((c & 1) ? 0 : 8160);
            __syncthreads();
        }
    }
    __syncthreads();          // stage-buffer readers done -> reuse as z-slab

    short* zs = lds + w * 4096;             // per-wave 32pix x 128short slab

    // BN shift + LeakyReLU -> bf16 z, XOR-swizzled writes (conflict-free)
#pragma unroll
    for (int mf = 0; mf < 6; ++mf)
#pragma unroll
        for (int p = 0; p < 2; ++p) {
            int pix = p * 16 + l15;
#pragma unroll
            for (int r = 0; r < 4; r += 2) {
                int co = mf * 16 + q * 4 + r;
                float z0 = acc[mf][p][r]     + shv[co];
                float z1 = acc[mf][p][r + 1] + shv[co + 1];
                z0 = z0 >= 0.f ? z0 : SLOPE * z0;
                z1 = z1 >= 0.f ? z1 : SLOPE * z1;
                unsigned pk = (unsigned)f2b(z0) | ((unsigned)f2b(z1) << 16);
                int c8 = mf * 2 + (q >> 1);
                int zi = pix * 128 + ((c8 ^ l15) * 8) + (q & 1) * 4 + r;
                *(unsigned*)&zs[zi] = pk;
            }
        }

    // desc 1x1 via MFMA, K=96 (XOR-swizzled b128 reads, conflict-free)
    f32x4 dacc[6][2];
#pragma unroll
    for (int mf = 0; mf < 6; ++mf) { dacc[mf][0] = fz; dacc[mf][1] = fz; }
    const bf16x8* __restrict__ dv = (const bf16x8*)packD;
#pragma unroll
    for (int s2 = 0; s2 < 3; ++s2) {
        int ch16 = s2 * 4 + q;
        bf16x8 B0 = *(const bf16x8*)&zs[l15 * 128        + ((ch16 ^ l15) * 8)];
        bf16x8 B1 = *(const bf16x8*)&zs[(16 + l15) * 128 + ((ch16 ^ l15) * 8)];
        const bf16x8* df = dv + (s2 * 6) * 64 + lane;
#pragma unroll
        for (int mf = 0; mf < 6; ++mf) {
            bf16x8 A = df[mf * 64];
            dacc[mf][0] = __builtin_amdgcn_mfma_f32_16x16x32_bf16(A, B0, dacc[mf][0], 0, 0, 0);
            dacc[mf][1] = __builtin_amdgcn_mfma_f32_16x16x32_bf16(A, B1, dacc[mf][1], 0, 0, 0);
        }
    }

    // bias + L2 norm (reduce over lane quarters)
    float ss0 = 0.f, ss1 = 0.f;
#pragma unroll
    for (int mf = 0; mf < 6; ++mf)
#pragma unroll
        for (int r = 0; r < 4; ++r) {
            int o = mf * 16 + q * 4 + r;
            float bias = desc_b[o];
            float d0 = dacc[mf][0][r] + bias;
            float d1 = dacc[mf][1][r] + bias;
            dacc[mf][0][r] = d0; dacc[mf][1][r] = d1;
            ss0 += d0 * d0; ss1 += d1 * d1;
        }
    ss0 += __shfl_xor(ss0, 16, 64); ss0 += __shfl_xor(ss0, 32, 64);
    ss1 += __shfl_xor(ss1, 16, 64); ss1 += __shfl_xor(ss1, 32, 64);
    const float rn0 = 1.f / sqrtf(ss0), rn1 = 1.f / sqrtf(ss1);

    // normalized bf16 back into the slab (same swizzle), same-wave ordering
#pragma unroll
    for (int mf = 0; mf < 6; ++mf)
#pragma unroll
        for (int p = 0; p < 2; ++p) {
            int pix = p * 16 + l15;
            float rn = p ? rn1 : rn0;
#pragma unroll
            for (int r = 0; r < 4; r += 2) {
                float d0 = dacc[mf][p][r]     * rn;
                float d1 = dacc[mf][p][r + 1] * rn;
                unsigned pk = (unsigned)f2b(d0) | ((unsigned)f2b(d1) << 16);
                int c8 = mf * 2 + (q >> 1);
                int zi = pix * 128 + ((c8 ^ l15) * 8) + (q & 1) * 4 + r;
                *(unsigned*)&zs[zi] = pk;
            }
        }

    // cooperative coalesced store: wave slab -> feat[z][y0+w][x0..x0+32][c]
    short* __restrict__ fo = feat + (((size_t)z * HH + y0 + w) * WW + x0) * CH;
#pragma unroll
    for (int it = 0; it < 6; ++it) {
        int cid = it * 64 + lane;              // 384 chunks = 32pix x 12
        int pix = cid / 12, c16 = cid - pix * 12;
        bf16x8 v = *(const bf16x8*)&zs[pix * 128 + ((c16 ^ (pix & 15)) * 8)];
        *(bf16x8*)&fo[pix * 96 + c16 * 8] = v;
    }
#undef STAGE_LOAD
#undef STAGE_WRITE
}

// ---------------------------------------------------------------------------
// Cost volume via MFMA, R6 restructure for parallelism + coalesced stores.
// Grid (5,160,4) = 3200 blocks. Block covers 64 x-cols; wave w owns x-tile
// [X0+16w, X0+16w+16) and its 4 B-groups fully in registers.
// B staged [col][c], col = x' - (X0-48), 112 cols, 13 chunks/col (pitch 104
// shorts: lane stride 52 dwords == 20 mod 32 -> bank-spread; chunk 12 = pad,
// dup-loaded, never read). Left-edge cols (bx==0) re-zeroed after staging.
// d = 48 - 16g + q*4 + r - l15; every (d, xl) covered exactly once.
// Output routed through LDS tile [49][73] -> 256B-contiguous d-row stores.
// LDS: ylds 1472 chunks (23552 B) union otile (14308 B).
// ---------------------------------------------------------------------------
__launch_bounds__(256, 4)
__global__ void cost_mfma_kernel(const short* __restrict__ xF,
                                 const short* __restrict__ yF,
                                 float* __restrict__ out)
{
    __shared__ __align__(16) char smem[23552];
    short* ylds  = (short*)smem;
    float* otile = (float*)smem;

    const int tid = threadIdx.x, lane = tid & 63, w = tid >> 6;
    const int q = lane >> 4, l15 = lane & 15;
    const int bx = blockIdx.x, y = blockIdx.y, b = blockIdx.z;
    const int X0 = bx * 64;

    const bf16x8 vz8 = {0, 0, 0, 0, 0, 0, 0, 0};
    const f32x4  fz  = {0.f, 0.f, 0.f, 0.f};

    // A-fragments first: independent of LDS, latency hides under staging.
    const size_t xbase = ((size_t)b * HH + y) * WW * CH;
    bf16x8 Af[3];
#pragma unroll
    for (int s2 = 0; s2 < 3; ++s2)
        Af[s2] = *(const bf16x8*)(xF + xbase +
                 (size_t)(X0 + 16 * w + l15) * CH + s2 * 32 + q * 8);

    // stage 1456 (+16 pad) chunks of Y row via global_load_lds (linear dest)
    const size_t ybase = ((size_t)(4 + b) * HH + y) * WW * CH;
    for (int wl = w; wl < 23; wl += 4) {
        int cb  = wl * 64;                             // wave-uniform
        int cid = cb + lane;
        int c2  = cid < 1456 ? cid : 1455;             // LDS pad slots
        int col = c2 / 13, ch = c2 - col * 13;
        if (ch == 12) ch = 0;                          // pitch-pad slot
        int xp = X0 - 48 + col;
        if (xp < 0) xp = 0;                            // re-zeroed below
        const short* gp = yF + ybase + (size_t)xp * CH + ch * 8;
        __builtin_amdgcn_global_load_lds(
            (const __attribute__((address_space(1))) unsigned int*)gp,
            (__attribute__((address_space(3))) unsigned int*)&ylds[(size_t)cb * 8],
            16, 0, 0);
    }
    __syncthreads();                                   // drains vmcnt

    if (bx == 0) {                                     // exact zeros for x'<0
        for (int e = tid; e < 624; e += 256)
            *(bf16x8*)&ylds[e * 8] = vz8;
        __syncthreads();
    }

    // B-fragments: 4 groups x 3 K-steps, all in registers
    bf16x8 Bf[4][3];
#pragma unroll
    for (int g = 0; g < 4; ++g)
#pragma unroll
        for (int s2 = 0; s2 < 3; ++s2)
            Bf[g][s2] = *(const bf16x8*)&ylds[(16 * (w + g) + l15) * 104
                                              + (s2 * 4 + q) * 8];
    __syncthreads();           // all ylds reads done -> safe to reuse as otile

    f32x4 acc[4] = {fz, fz, fz, fz};
#pragma unroll
    for (int g = 0; g < 4; ++g)
#pragma unroll
        for (int s2 = 0; s2 < 3; ++s2)
            acc[g] = __builtin_amdgcn_mfma_f32_16x16x32_bf16(Af[s2], Bf[g][s2],
                                                             acc[g], 0, 0, 0);

    // scatter into LDS out-tile (pitch 73 -> 2-way max on banks)
#pragma unroll
    for (int g = 0; g < 4; ++g)
#pragma unroll
        for (int r = 0; r < 4; ++r) {
            int d = 48 - 16 * g + q * 4 + r - l15;
            if (0 <= d && d <= 48)
                otile[d * 73 + 16 * w + q * 4 + r] = acc[g][r];
        }
    __syncthreads();

    // coalesced store: each d-row = 64 contiguous floats (256 B)
    for (int e = tid; e < 49 * 64; e += 256) {
        int d = e >> 6, xl = e & 63;
        out[((size_t)(d * BATCH + b) * HH + y) * WW + X0 + xl] = otile[d * 73 + xl];
    }
}

// ---------------------------------------------------------------------------
extern "C" void kernel_launch(void* const* d_in, const int* in_sizes, int n_in,
                              void* d_out, int out_size, void* d_ws, size_t ws_size,
                              hipStream_t stream)
{
    const float* imL      = (const float*)d_in[0];
    const float* imR      = (const float*)d_in[1];
    const float* conv_w   = (const float*)d_in[2];
    const float* bn_gamma = (const float*)d_in[3];
    const float* bn_beta  = (const float*)d_in[4];
    const float* bn_mean  = (const float*)d_in[5];
    const float* bn_var   = (const float*)d_in[6];
    const float* desc_w   = (const float*)d_in[7];
    const float* desc_b   = (const float*)d_in[8];

    // d_ws: imT bf16 [8][160][320][96] | feat bf16 [8][160][320][96]
    const size_t half = (size_t)8 * HH * WW * CH;
    short* imT  = (short*)d_ws;
    short* feat = (short*)d_ws + half;

    // pack buffers in the head of d_out; consumed by feat_mfma BEFORE
    // cost_mfma overwrites d_out (same-stream ordering).
    short* packW = (short*)d_out;                      // 165,888 B
    short* packD = (short*)((char*)d_out + 165888);    //  18,432 B
    float* shv   = (float*)((char*)d_out + 184320);    //     384 B

    dim3 tgrid(WW / 64, HH, 2 * BATCH);                // (5,160,8)
    transpose_kernel<<<tgrid, 256, 0, stream>>>(imL, imR, imT);

    pack_kernel<<<361, 256, 0, stream>>>(conv_w, bn_gamma, bn_beta, bn_mean,
                                         bn_var, desc_w, packW, packD, shv);

    dim3 fgrid(WW / 32, HH / 4, 2 * BATCH);            // (10,40,8)
    feat_mfma_kernel<<<fgrid, 256, 0, stream>>>(imT, packW, packD, shv,
                                                desc_b, feat);

    // feat base passed for BOTH X and Y; kernel selects z=b (L) / z=4+b (R).
    dim3 cgrid(5, HH, BATCH);                          // (5,160,4)
    cost_mfma_kernel<<<cgrid, 256, 0, stream>>>(feat, feat, (float*)d_out);
}

// Round 7
// 334.265 us; speedup vs baseline: 22.1269x; 1.1373x over previous
//
#include <hip/hip_runtime.h>
#include <hip/hip_bf16.h>

#define BATCH 4
#define CH    96
#define HH    160
#define WW    320
#define MAXD  49
#define BN_EPS 1e-5f
#define SLOPE  0.01f

typedef __attribute__((ext_vector_type(8))) short bf16x8;
typedef __attribute__((ext_vector_type(4))) float f32x4;

__device__ __forceinline__ ushort f2b(float f) {
    __hip_bfloat16 h = __float2bfloat16(f);            // RNE
    return *reinterpret_cast<ushort*>(&h);
}

// ---------------------------------------------------------------------------
// 0a: f32 NCHW image -> bf16 [img*4+b][y][x][ci] (ci innermost). Unchanged.
// ---------------------------------------------------------------------------
__launch_bounds__(256)
__global__ void transpose_kernel(const float* __restrict__ imL,
                                 const float* __restrict__ imR,
                                 short* __restrict__ imT)
{
    __shared__ ushort tile[96 * 74];
    const int t  = threadIdx.x;
    const int x0 = blockIdx.x * 64;
    const int y  = blockIdx.y;
    const int z  = blockIdx.z;             // img*4+b
    const int b = z & 3, img = z >> 2;
    const float* __restrict__ im = img ? imR : imL;
    for (int e = t; e < 96 * 64; e += 256) {
        int ci = e >> 6, x = e & 63;
        tile[ci * 74 + x] = f2b(im[((b * CH + ci) * HH + y) * WW + x0 + x]);
    }
    __syncthreads();
    short* __restrict__ out = imT + (((size_t)z * HH + y) * WW + x0) * CH;
    for (int e = t; e < 64 * 96; e += 256) {
        int x = e / 96, ci = e - x * 96;
        out[e] = (short)tile[ci * 74 + x];
    }
}

// ---------------------------------------------------------------------------
// 0b: pack conv weights (BN scale folded) + desc weights into exact
// mfma_f32_16x16x32_bf16 A-fragment order (lane l: m=l&15, k=(l>>4)*8+j).
// ---------------------------------------------------------------------------
__launch_bounds__(256)
__global__ void pack_kernel(const float* __restrict__ conv_w,
                            const float* __restrict__ bn_gamma,
                            const float* __restrict__ bn_beta,
                            const float* __restrict__ bn_mean,
                            const float* __restrict__ bn_var,
                            const float* __restrict__ desc_w,
                            short* __restrict__ packW,   // 82944 bf16
                            short* __restrict__ packD,   // 9216 bf16
                            float* __restrict__ shv)     // 96 f32
{
    int id = blockIdx.x * 256 + threadIdx.x;
    if (id < 82944) {
        int j = id & 7, l = (id >> 3) & 63;
        int rest = id >> 9;                    // (chunk*9+tap)*6+mf
        int mf = rest % 6; int r2 = rest / 6;
        int tp = r2 % 9;  int chunk = r2 / 9;
        int co = mf * 16 + (l & 15);
        int ci = chunk * 32 + ((l >> 4) << 3) + j;
        float sc = bn_gamma[co] / sqrtf(bn_var[co] + BN_EPS);
        packW[id] = (short)f2b(conv_w[(co * 96 + ci) * 9 + tp] * sc);
    } else if (id < 92160) {
        int d = id - 82944;
        int j = d & 7, l = (d >> 3) & 63;
        int rest = d >> 9;                     // s2*6+mf
        int mf = rest % 6, s2 = rest / 6;
        int o = mf * 16 + (l & 15);
        int c = s2 * 32 + ((l >> 4) << 3) + j;
        packD[d] = (short)f2b(desc_w[o * 96 + c]);
    } else if (id < 92256) {
        int co = id - 92160;
        float sc = bn_gamma[co] / sqrtf(bn_var[co] + BN_EPS);
        shv[co] = bn_beta[co] - bn_mean[co] * sc;
    }
}

// ---------------------------------------------------------------------------
// Fused MFMA feature kernel. R7: explicit A-fragment double-buffer
// (Apre/Acur) pipelines the 54 per-chunk weight loads across taps instead of
// serializing each against vmcnt(0) (R6's VGPR_Count=64 left zero prefetch
// headroom). STAGE_LOAD moved to the tap-2 slot so its HBM loads enter the
// vmcnt FIFO after tap-3's A-loads (FIFO drain decoupling). Desc s2-loads
// pipelined the same way via the same rolling buffer.
// ---------------------------------------------------------------------------
__launch_bounds__(256, 3)
__global__ void feat_mfma_kernel(const short* __restrict__ imT,
                                 const short* __restrict__ packW,
                                 const short* __restrict__ packD,
                                 const float* __restrict__ shv,
                                 const float* __restrict__ desc_b,
                                 short* __restrict__ feat)
{
    // union: stage bufA [0,8160) bufB [8160,16320)  /  z-slab [0,16384)
    __shared__ __align__(16) short lds[16384];          // 32 KiB

    const int tid  = threadIdx.x;
    const int lane = tid & 63, w = tid >> 6;
    const int q = lane >> 4, l15 = lane & 15;
    const int x0 = blockIdx.x * 32, y0 = blockIdx.y * 4;
    const int z  = blockIdx.z;                          // img*4+b
    const size_t imbase = (size_t)z * HH * WW * CH;

    const bf16x8 vz8 = {0, 0, 0, 0, 0, 0, 0, 0};
    const f32x4  fz  = {0.f, 0.f, 0.f, 0.f};

    f32x4 acc[6][2];
#pragma unroll
    for (int mf = 0; mf < 6; ++mf) { acc[mf][0] = fz; acc[mf][1] = fz; }

    const bf16x8* __restrict__ wv = (const bf16x8*)packW;
    const bf16x8* __restrict__ dv = (const bf16x8*)packD;
    bf16x8 sv[4];
    bf16x8 Apre[6], Acur[6];

#define STAGE_LOAD(chunk)                                                      \
    {                                                                          \
        _Pragma("unroll")                                                      \
        for (int k = 0; k < 4; ++k) {                                          \
            int e = tid + k * 256;                                             \
            bf16x8 v = vz8;                                                    \
            if (e < 816) {                                                     \
                int r = e / 136, rem = e - r * 136;                            \
                int cc = rem >> 2, g = rem & 3;                                \
                int gy = y0 - 1 + r, gx = x0 - 1 + cc;                         \
                if ((unsigned)gy < HH && (unsigned)gx < WW)                    \
                    v = *(const bf16x8*)(imT + imbase +                        \
                        ((size_t)gy * WW + gx) * CH + (chunk) * 32 + g * 8);   \
            }                                                                  \
            sv[k] = v;                                                         \
        }                                                                      \
    }

#define STAGE_WRITE(bufofs)                                                    \
    {                                                                          \
        _Pragma("unroll")                                                      \
        for (int k = 0; k < 4; ++k) {                                          \
            int e = tid + k * 256;                                             \
            if (e < 816) {                                                     \
                int r = e / 136, rem = e - r * 136;                            \
                int cc = rem >> 2, g = rem & 3;                                \
                *(bf16x8*)&lds[(bufofs) + (r * 34 + cc) * 40 + g * 8] = sv[k]; \
            }                                                                  \
        }                                                                      \
    }

    STAGE_LOAD(0);
    STAGE_WRITE(0);
    __syncthreads();

    // cold prologue: chunk 0 / tap 0 weight fragments
    {
        const bf16x8* wf = wv + lane;
#pragma unroll
        for (int mf = 0; mf < 6; ++mf) Apre[mf] = wf[mf * 64];
    }

#pragma unroll
    for (int c = 0; c < 3; ++c) {
        const int bo = (c & 1) ? 8160 : 0;
#pragma unroll
        for (int tp = 0; tp < 9; ++tp) {
            // consume the prefetched fragments
#pragma unroll
            for (int mf = 0; mf < 6; ++mf) Acur[mf] = Apre[mf];
            // issue next prefetch: next tap, next chunk's tap 0, or desc s2=0
            if (tp < 8) {
                const bf16x8* wf = wv + ((c * 9 + tp + 1) * 6) * 64 + lane;
#pragma unroll
                for (int mf = 0; mf < 6; ++mf) Apre[mf] = wf[mf * 64];
            } else if (c < 2) {
                const bf16x8* wf = wv + (((c + 1) * 9) * 6) * 64 + lane;
#pragma unroll
                for (int mf = 0; mf < 6; ++mf) Apre[mf] = wf[mf * 64];
            } else {
                const bf16x8* df = dv + lane;
#pragma unroll
                for (int mf = 0; mf < 6; ++mf) Apre[mf] = df[mf * 64];
            }
            // staging loads issued AFTER tap-3's A-loads (vmcnt FIFO order)
            if (tp == 2 && c < 2) STAGE_LOAD(c + 1);

            const int dy = tp / 3, dx = tp - dy * 3;
            const int cell = (w + dy) * 34 + l15 + dx;
            bf16x8 B0 = *(const bf16x8*)&lds[bo + cell * 40 + q * 8];
            bf16x8 B1 = *(const bf16x8*)&lds[bo + (cell + 16) * 40 + q * 8];
#pragma unroll
            for (int mf = 0; mf < 6; ++mf) {
                acc[mf][0] = __builtin_amdgcn_mfma_f32_16x16x32_bf16(Acur[mf], B0, acc[mf][0], 0, 0, 0);
                acc[mf][1] = __builtin_amdgcn_mfma_f32_16x16x32_bf16(Acur[mf], B1, acc[mf][1], 0, 0, 0);
            }
        }
        if (c < 2) {
            STAGE_WRITE((c & 1) ? 0 : 8160);
            __syncthreads();
        }
    }
    __syncthreads();          // stage-buffer readers done -> reuse as z-slab

    short* zs = lds + w * 4096;             // per-wave 32pix x 128short slab

    // BN shift + LeakyReLU -> bf16 z, XOR-swizzled writes (conflict-free)
#pragma unroll
    for (int mf = 0; mf < 6; ++mf)
#pragma unroll
        for (int p = 0; p < 2; ++p) {
            int pix = p * 16 + l15;
#pragma unroll
            for (int r = 0; r < 4; r += 2) {
                int co = mf * 16 + q * 4 + r;
                float z0 = acc[mf][p][r]     + shv[co];
                float z1 = acc[mf][p][r + 1] + shv[co + 1];
                z0 = z0 >= 0.f ? z0 : SLOPE * z0;
                z1 = z1 >= 0.f ? z1 : SLOPE * z1;
                unsigned pk = (unsigned)f2b(z0) | ((unsigned)f2b(z1) << 16);
                int c8 = mf * 2 + (q >> 1);
                int zi = pix * 128 + ((c8 ^ l15) * 8) + (q & 1) * 4 + r;
                *(unsigned*)&zs[zi] = pk;
            }
        }

    // desc 1x1 via MFMA, K=96; s2-level prefetch through the rolling buffer
    f32x4 dacc[6][2];
#pragma unroll
    for (int mf = 0; mf < 6; ++mf) { dacc[mf][0] = fz; dacc[mf][1] = fz; }
#pragma unroll
    for (int s2 = 0; s2 < 3; ++s2) {
#pragma unroll
        for (int mf = 0; mf < 6; ++mf) Acur[mf] = Apre[mf];
        if (s2 < 2) {
            const bf16x8* df = dv + ((s2 + 1) * 6) * 64 + lane;
#pragma unroll
            for (int mf = 0; mf < 6; ++mf) Apre[mf] = df[mf * 64];
        }
        int ch16 = s2 * 4 + q;
        bf16x8 B0 = *(const bf16x8*)&zs[l15 * 128        + ((ch16 ^ l15) * 8)];
        bf16x8 B1 = *(const bf16x8*)&zs[(16 + l15) * 128 + ((ch16 ^ l15) * 8)];
#pragma unroll
        for (int mf = 0; mf < 6; ++mf) {
            dacc[mf][0] = __builtin_amdgcn_mfma_f32_16x16x32_bf16(Acur[mf], B0, dacc[mf][0], 0, 0, 0);
            dacc[mf][1] = __builtin_amdgcn_mfma_f32_16x16x32_bf16(Acur[mf], B1, dacc[mf][1], 0, 0, 0);
        }
    }

    // bias + L2 norm (reduce over lane quarters)
    float ss0 = 0.f, ss1 = 0.f;
#pragma unroll
    for (int mf = 0; mf < 6; ++mf)
#pragma unroll
        for (int r = 0; r < 4; ++r) {
            int o = mf * 16 + q * 4 + r;
            float bias = desc_b[o];
            float d0 = dacc[mf][0][r] + bias;
            float d1 = dacc[mf][1][r] + bias;
            dacc[mf][0][r] = d0; dacc[mf][1][r] = d1;
            ss0 += d0 * d0; ss1 += d1 * d1;
        }
    ss0 += __shfl_xor(ss0, 16, 64); ss0 += __shfl_xor(ss0, 32, 64);
    ss1 += __shfl_xor(ss1, 16, 64); ss1 += __shfl_xor(ss1, 32, 64);
    const float rn0 = 1.f / sqrtf(ss0), rn1 = 1.f / sqrtf(ss1);

    // normalized bf16 back into the slab (same swizzle), same-wave ordering
#pragma unroll
    for (int mf = 0; mf < 6; ++mf)
#pragma unroll
        for (int p = 0; p < 2; ++p) {
            int pix = p * 16 + l15;
            float rn = p ? rn1 : rn0;
#pragma unroll
            for (int r = 0; r < 4; r += 2) {
                float d0 = dacc[mf][p][r]     * rn;
                float d1 = dacc[mf][p][r + 1] * rn;
                unsigned pk = (unsigned)f2b(d0) | ((unsigned)f2b(d1) << 16);
                int c8 = mf * 2 + (q >> 1);
                int zi = pix * 128 + ((c8 ^ l15) * 8) + (q & 1) * 4 + r;
                *(unsigned*)&zs[zi] = pk;
            }
        }

    // cooperative coalesced store: wave slab -> feat[z][y0+w][x0..x0+32][c]
    short* __restrict__ fo = feat + (((size_t)z * HH + y0 + w) * WW + x0) * CH;
#pragma unroll
    for (int it = 0; it < 6; ++it) {
        int cid = it * 64 + lane;              // 384 chunks = 32pix x 12
        int pix = cid / 12, c16 = cid - pix * 12;
        bf16x8 v = *(const bf16x8*)&zs[pix * 128 + ((c16 ^ (pix & 15)) * 8)];
        *(bf16x8*)&fo[pix * 96 + c16 * 8] = v;
    }
#undef STAGE_LOAD
#undef STAGE_WRITE
}

// ---------------------------------------------------------------------------
// Cost volume via MFMA (unchanged from R6).
// ---------------------------------------------------------------------------
__launch_bounds__(256, 4)
__global__ void cost_mfma_kernel(const short* __restrict__ xF,
                                 const short* __restrict__ yF,
                                 float* __restrict__ out)
{
    __shared__ __align__(16) char smem[23552];
    short* ylds  = (short*)smem;
    float* otile = (float*)smem;

    const int tid = threadIdx.x, lane = tid & 63, w = tid >> 6;
    const int q = lane >> 4, l15 = lane & 15;
    const int bx = blockIdx.x, y = blockIdx.y, b = blockIdx.z;
    const int X0 = bx * 64;

    const bf16x8 vz8 = {0, 0, 0, 0, 0, 0, 0, 0};
    const f32x4  fz  = {0.f, 0.f, 0.f, 0.f};

    // A-fragments first: independent of LDS, latency hides under staging.
    const size_t xbase = ((size_t)b * HH + y) * WW * CH;
    bf16x8 Af[3];
#pragma unroll
    for (int s2 = 0; s2 < 3; ++s2)
        Af[s2] = *(const bf16x8*)(xF + xbase +
                 (size_t)(X0 + 16 * w + l15) * CH + s2 * 32 + q * 8);

    // stage 1456 (+16 pad) chunks of Y row via global_load_lds (linear dest)
    const size_t ybase = ((size_t)(4 + b) * HH + y) * WW * CH;
    for (int wl = w; wl < 23; wl += 4) {
        int cb  = wl * 64;                             // wave-uniform
        int cid = cb + lane;
        int c2  = cid < 1456 ? cid : 1455;             // LDS pad slots
        int col = c2 / 13, ch = c2 - col * 13;
        if (ch == 12) ch = 0;                          // pitch-pad slot
        int xp = X0 - 48 + col;
        if (xp < 0) xp = 0;                            // re-zeroed below
        const short* gp = yF + ybase + (size_t)xp * CH + ch * 8;
        __builtin_amdgcn_global_load_lds(
            (const __attribute__((address_space(1))) unsigned int*)gp,
            (__attribute__((address_space(3))) unsigned int*)&ylds[(size_t)cb * 8],
            16, 0, 0);
    }
    __syncthreads();                                   // drains vmcnt

    if (bx == 0) {                                     // exact zeros for x'<0
        for (int e = tid; e < 624; e += 256)
            *(bf16x8*)&ylds[e * 8] = vz8;
        __syncthreads();
    }

    // B-fragments: 4 groups x 3 K-steps, all in registers
    bf16x8 Bf[4][3];
#pragma unroll
    for (int g = 0; g < 4; ++g)
#pragma unroll
        for (int s2 = 0; s2 < 3; ++s2)
            Bf[g][s2] = *(const bf16x8*)&ylds[(16 * (w + g) + l15) * 104
                                              + (s2 * 4 + q) * 8];
    __syncthreads();           // all ylds reads done -> safe to reuse as otile

    f32x4 acc[4] = {fz, fz, fz, fz};
#pragma unroll
    for (int g = 0; g < 4; ++g)
#pragma unroll
        for (int s2 = 0; s2 < 3; ++s2)
            acc[g] = __builtin_amdgcn_mfma_f32_16x16x32_bf16(Af[s2], Bf[g][s2],
                                                             acc[g], 0, 0, 0);

    // scatter into LDS out-tile (pitch 73 -> 2-way max on banks)
#pragma unroll
    for (int g = 0; g < 4; ++g)
#pragma unroll
        for (int r = 0; r < 4; ++r) {
            int d = 48 - 16 * g + q * 4 + r - l15;
            if (0 <= d && d <= 48)
                otile[d * 73 + 16 * w + q * 4 + r] = acc[g][r];
        }
    __syncthreads();

    // coalesced store: each d-row = 64 contiguous floats (256 B)
    for (int e = tid; e < 49 * 64; e += 256) {
        int d = e >> 6, xl = e & 63;
        out[((size_t)(d * BATCH + b) * HH + y) * WW + X0 + xl] = otile[d * 73 + xl];
    }
}

// ---------------------------------------------------------------------------
extern "C" void kernel_launch(void* const* d_in, const int* in_sizes, int n_in,
                              void* d_out, int out_size, void* d_ws, size_t ws_size,
                              hipStream_t stream)
{
    const float* imL      = (const float*)d_in[0];
    const float* imR      = (const float*)d_in[1];
    const float* conv_w   = (const float*)d_in[2];
    const float* bn_gamma = (const float*)d_in[3];
    const float* bn_beta  = (const float*)d_in[4];
    const float* bn_mean  = (const float*)d_in[5];
    const float* bn_var   = (const float*)d_in[6];
    const float* desc_w   = (const float*)d_in[7];
    const float* desc_b   = (const float*)d_in[8];

    // d_ws: imT bf16 [8][160][320][96] | feat bf16 [8][160][320][96]
    const size_t half = (size_t)8 * HH * WW * CH;
    short* imT  = (short*)d_ws;
    short* feat = (short*)d_ws + half;

    // pack buffers in the head of d_out; consumed by feat_mfma BEFORE
    // cost_mfma overwrites d_out (same-stream ordering).
    short* packW = (short*)d_out;                      // 165,888 B
    short* packD = (short*)((char*)d_out + 165888);    //  18,432 B
    float* shv   = (float*)((char*)d_out + 184320);    //     384 B

    dim3 tgrid(WW / 64, HH, 2 * BATCH);                // (5,160,8)
    transpose_kernel<<<tgrid, 256, 0, stream>>>(imL, imR, imT);

    pack_kernel<<<361, 256, 0, stream>>>(conv_w, bn_gamma, bn_beta, bn_mean,
                                         bn_var, desc_w, packW, packD, shv);

    dim3 fgrid(WW / 32, HH / 4, 2 * BATCH);            // (10,40,8)
    feat_mfma_kernel<<<fgrid, 256, 0, stream>>>(imT, packW, packD, shv,
                                                desc_b, feat);

    // feat base passed for BOTH X and Y; kernel selects z=b (L) / z=4+b (R).
    dim3 cgrid(5, HH, BATCH);                          // (5,160,4)
    cost_mfma_kernel<<<cgrid, 256, 0, stream>>>(feat, feat, (float*)d_out);
}